// Round 3
// baseline (241.253 us; speedup 1.0000x reference)
//
#include <hip/hip_runtime.h>
#include <hip/hip_bf16.h>
#include <stdint.h>

typedef __bf16 bf16x8 __attribute__((ext_vector_type(8)));
typedef float f32x4 __attribute__((ext_vector_type(4)));

#define GLD16(gp, lp) __builtin_amdgcn_global_load_lds( \
    (__attribute__((address_space(1))) void*)(gp),      \
    (__attribute__((address_space(3))) void*)(lp), 16, 0, 0)

// Sizes
#define Bb 4
#define Nn 8192
#define Mm 2048
#define Cc 512
#define Ll 256
#define Hh 8
#define NTOK 32768   // Bb*Nn

// ---------------- convert Q f32 -> bf16 (row-major) -------------------------
__global__ __launch_bounds__(256) void convert_q(
    const float* __restrict__ Q, __hip_bfloat16* __restrict__ Qb)
{
    long i = ((long)blockIdx.x * 256 + threadIdx.x) * 8;   // < 4194304
    float4 a = *(const float4*)(Q + i);
    float4 b = *(const float4*)(Q + i + 4);
    __hip_bfloat16 t8[8] = {
        __float2bfloat16(a.x), __float2bfloat16(a.y),
        __float2bfloat16(a.z), __float2bfloat16(a.w),
        __float2bfloat16(b.x), __float2bfloat16(b.y),
        __float2bfloat16(b.z), __float2bfloat16(b.w)};
    *(uint4*)(Qb + i) = *(const uint4*)t8;
}

// ---------------- transpose_x: X f32 [32768][512] -> Xb [n][c], XbT [c][n] --
// 64x64 tiles via padded LDS.
__global__ __launch_bounds__(256) void transpose_x(
    const float* __restrict__ X,
    __hip_bfloat16* __restrict__ Xb, __hip_bfloat16* __restrict__ XbT)
{
    __shared__ __hip_bfloat16 ldsT[64][72];   // [c][n] padded
    const int tn = blockIdx.x, tc = blockIdx.y;
    const long n0 = (long)tn * 64;
    const int c0 = tc * 64;
    const int t = threadIdx.x;
    const int rl = t >> 4;           // 0..15
    const int c4 = (t & 15) * 4;     // 0..60
#pragma unroll
    for (int u = 0; u < 4; ++u) {
        const int row = rl + u * 16; // 0..63
        f32x4 a = *(const f32x4*)(X + (n0 + row) * Cc + c0 + c4);
        __hip_bfloat16 b4[4] = {
            __float2bfloat16(a.x), __float2bfloat16(a.y),
            __float2bfloat16(a.z), __float2bfloat16(a.w)};
        *(ushort2*)(&Xb[(n0 + row) * Cc + c0 + c4]) = *(const ushort2*)b4;
        *(ushort2*)(&Xb[(n0 + row) * Cc + c0 + c4 + 2]) = *(const ushort2*)(b4 + 2);
#pragma unroll
        for (int i = 0; i < 4; ++i) ldsT[c4 + i][row] = b4[i];
    }
    __syncthreads();
#pragma unroll
    for (int u = 0; u < 2; ++u) {
        const int v = u * 256 + t;
        const int orow = v >> 3;        // c index 0..63
        const int oc8 = (v & 7) * 8;    // n offset 0..56
        bf16x8 r = *(const bf16x8*)(&ldsT[orow][oc8]);
        *(bf16x8*)(&XbT[(long)(c0 + orow) * NTOK + n0 + oc8]) = r;
    }
}

// ---------------- transpose weights: WkT[d][c]=Wk[c][d], WqT[j][c]=Wq[c][j] -
__global__ __launch_bounds__(256) void transpose_w2(
    const float* __restrict__ Wk, const float* __restrict__ Wq,
    __hip_bfloat16* __restrict__ WkT, __hip_bfloat16* __restrict__ WqT)
{
    int idx = blockIdx.x * 256 + threadIdx.x;  // < 262144
    const int NK = 256 * 512;
    if (idx < NK) {
        int j = idx >> 9, c = idx & 511;
        WkT[idx] = __float2bfloat16(Wk[c * 256 + j]);
    } else {
        int k = idx - NK;
        int j = k >> 9, c = k & 511;
        WqT[k] = __float2bfloat16(Wq[c * 256 + j]);
    }
}

// ---------------- GEMM: C = A(MxK) @ Bt(NxK)^T, bf16, 2-phase dbuf ---------
// MODE 0 (kT):  bias by ROW (d), ELU+1, bf16 out, C[row*ldc+col]
// MODE 1 (q):   bias by COL, ELU+1, bf16 out, C[row*ldc+col]
// MODE 2 (xk):  no bias/act, f32 out partial slice per blockIdx.z
template<int MODE>
__global__ __launch_bounds__(256)
void gemm_bt(const __hip_bfloat16* __restrict__ A, long lda,
             const __hip_bfloat16* __restrict__ Bt, long ldb,
             const float* __restrict__ bias,
             void* __restrict__ Cout, long ldc, int Klen)
{
    __shared__ char lds[2][16384];   // [buf][A 8KB | B 8KB]
    const int tid  = threadIdx.x;
    const int lane = tid & 63;
    const int wv   = tid >> 6;
    const int wm   = wv >> 1, wn = wv & 1;
    const long gm0 = (long)blockIdx.x * 128;
    const long gn0 = (long)blockIdx.y * 128;

    long koff_el = 0;
    if (MODE == 2) {
        const int z = blockIdx.z;
        koff_el = (long)(z >> 3) * Nn + (long)(z & 7) * 1024;
    }

    const int o0 = tid * 16;         // 0..4095
    const int row0 = o0 >> 6;        // 0..63
    const int kb0 = o0 & 63;
    const int o1 = o0 + 4096;
    const int row1 = row0 + 64;
    const long sA = lda * 2, sB = ldb * 2;
    const char* pA0 = (const char*)A + (gm0 + row0) * sA + koff_el * 2 + kb0;
    const char* pA1 = (const char*)A + (gm0 + row1) * sA + koff_el * 2 + kb0;
    const char* pB0 = (const char*)Bt + (gn0 + row0) * sB + koff_el * 2 + kb0;
    const char* pB1 = (const char*)Bt + (gn0 + row1) * sB + koff_el * 2 + kb0;

    f32x4 acc[4][4];
#pragma unroll
    for (int i = 0; i < 4; i++)
#pragma unroll
        for (int j = 0; j < 4; j++) acc[i][j] = (f32x4){0.f, 0.f, 0.f, 0.f};

    const int l16 = lane & 15, lq = lane >> 4;
    int aoff[4], boff[4];
#pragma unroll
    for (int i = 0; i < 4; i++) {
        aoff[i] = (wm * 64 + i * 16 + l16) * 64 + lq * 16;
        boff[i] = 8192 + (wn * 64 + i * 16 + l16) * 64 + lq * 16;
    }

    const int KT = Klen >> 5;
    // prologue: stage tile 0 into buf 0
    {
        char* bf = lds[0];
        GLD16(pA0, bf + o0); GLD16(pA1, bf + o1);
        GLD16(pB0, bf + 8192 + o0); GLD16(pB1, bf + 8192 + o1);
    }
    __syncthreads();
    for (int kt = 0; kt < KT; ++kt) {
        const int cur = kt & 1;
        if (kt + 1 < KT) {
            char* bf = lds[cur ^ 1];
            const long kb = (long)(kt + 1) * 64;
            GLD16(pA0 + kb, bf + o0); GLD16(pA1 + kb, bf + o1);
            GLD16(pB0 + kb, bf + 8192 + o0); GLD16(pB1 + kb, bf + 8192 + o1);
        }
        const char* lp = lds[cur];
        bf16x8 af[4], bfr[4];
#pragma unroll
        for (int i = 0; i < 4; i++) af[i]  = *(const bf16x8*)(lp + aoff[i]);
#pragma unroll
        for (int j = 0; j < 4; j++) bfr[j] = *(const bf16x8*)(lp + boff[j]);
#pragma unroll
        for (int i = 0; i < 4; i++)
#pragma unroll
            for (int j = 0; j < 4; j++)
                acc[i][j] = __builtin_amdgcn_mfma_f32_16x16x32_bf16(
                    af[i], bfr[j], acc[i][j], 0, 0, 0);
        __syncthreads();
    }

    // epilogue: C/D layout col=lane&15, row=(lane>>4)*4+reg  [m89-verified]
    __hip_bfloat16* Cb = (__hip_bfloat16*)Cout;
    float* Cf = (float*)Cout;
    if (MODE == 2) Cf += (long)blockIdx.z * (512 * 256);
#pragma unroll
    for (int i = 0; i < 4; i++) {
        const long gmr = gm0 + wm * 64 + i * 16 + lq * 4;
#pragma unroll
        for (int j = 0; j < 4; j++) {
            const int gn = (int)gn0 + wn * 64 + j * 16 + l16;
#pragma unroll
            for (int v = 0; v < 4; v++) {
                float x = acc[i][j][v];
                if (MODE == 0) {
                    x += bias[gmr + v];
                    x = (x > 0.f) ? x + 1.f : __expf(x);
                    Cb[(gmr + v) * ldc + gn] = __float2bfloat16(x);
                } else if (MODE == 1) {
                    x += bias[gn];
                    x = (x > 0.f) ? x + 1.f : __expf(x);
                    Cb[(gmr + v) * ldc + gn] = __float2bfloat16(x);
                } else {
                    Cf[(gmr + v) * ldc + gn] = x;
                }
            }
        }
    }
}

// ---------------- ksum[b][j] = sum_n kT[j][b*8192 + n] ----------------------
__global__ __launch_bounds__(256)
void ksum_kernel(const __hip_bfloat16* __restrict__ kT, float* __restrict__ ksum)
{
    const int j = blockIdx.x;   // 0..255 (= h*32+d)
    const int b = blockIdx.y;
    const int t = threadIdx.x;
    const __hip_bfloat16* row = kT + (long)j * NTOK + b * Nn + t * 32;
    float s = 0.f;
#pragma unroll
    for (int u = 0; u < 4; ++u) {
        bf16x8 kv8 = *(const bf16x8*)(row + u * 8);
#pragma unroll
        for (int e = 0; e < 8; ++e) s += (float)kv8[e];
    }
    __shared__ float red[256];
    red[t] = s;
    __syncthreads();
    for (int st = 128; st > 0; st >>= 1) {
        if (t < st) red[t] += red[t + st];
        __syncthreads();
    }
    if (t == 0) ksum[b * 256 + j] = red[0];
}

// ---------------- reduce xkpart (8 K-splits) -> xk --------------------------
__global__ __launch_bounds__(256)
void reduce_xk(const float* __restrict__ part, float* __restrict__ xk)
{
    int idx = blockIdx.x * 256 + threadIdx.x;   // < 524288 (=4*512*256)
    int b = idx >> 17, r = idx & 131071;
    const float* p = part + (long)b * 8 * 131072 + r;
    float s = 0.f;
#pragma unroll
    for (int ks = 0; ks < 8; ++ks) s += p[(long)ks * 131072];
    xk[idx] = s;
}

// ---------------- wv_contract: kvagg[b,h,c,d] = Wv^T . xk + bv*ksum ---------
// kvagg[((b*8+h)*64+c)*32+d] = sum_c' Wv[c',h*64+c]*xk[b,c',h*32+d]
//                              + bv[h*64+c]*ksum[b,h*32+d]
__global__ __launch_bounds__(256)
void wv_contract(const float* __restrict__ xk, const float* __restrict__ Wv,
                 const float* __restrict__ bv, const float* __restrict__ ksum,
                 float* __restrict__ kvagg)
{
    __shared__ float xs[512][32];   // 64KB
    const int chg = blockIdx.x;     // 0..31 (16 channels each)
    const int b = blockIdx.y;
    const int t = threadIdx.x;
    const int ch0 = chg * 16;
    const int h = ch0 >> 6;
    const float* xb = xk + (long)b * 131072 + h * 32;
#pragma unroll
    for (int u = 0; u < 16; ++u) {
        const int v = u * 256 + t;      // < 4096
        const int row = v >> 3, c4 = (v & 7) * 4;
        *(f32x4*)&xs[row][c4] = *(const f32x4*)&xb[(long)row * 256 + c4];
    }
    __syncthreads();
    const int ch_l = t >> 4;            // 0..15
    const int d0 = (t & 15) * 2;        // 0,2..30
    const int ch = ch0 + ch_l;
    float a0 = 0.f, a1 = 0.f;
#pragma unroll 8
    for (int c = 0; c < 512; ++c) {
        const float w = Wv[(long)c * 512 + ch];
        a0 = fmaf(w, xs[c][d0], a0);
        a1 = fmaf(w, xs[c][d0 + 1], a1);
    }
    const float bvv = bv[ch];
    const float* ks = ksum + b * 256 + h * 32;
    a0 += bvv * ks[d0];
    a1 += bvv * ks[d0 + 1];
    float* op = kvagg + (((long)(b * 8 + h) * 64 + (ch & 63)) * 32);
    op[d0] = a0;
    op[d0 + 1] = a1;
}

// ---------------- z[m][h] = 1/(q[m,h,:].ksum[b,h,:] + eps) ------------------
__global__ __launch_bounds__(256)
void z_kernel(const __hip_bfloat16* __restrict__ qb,
              const float* __restrict__ ksum, float* __restrict__ zb)
{
    int t = blockIdx.x * 256 + threadIdx.x;  // 65536 = 8192*8
    int m = t >> 3, h = t & 7;
    int b = m >> 11;
    const __hip_bfloat16* q = qb + (long)m * 256 + h * 32;
    const float* ks = ksum + ((long)b * Hh + h) * 32;
    float s = 0.f;
#pragma unroll
    for (int d8 = 0; d8 < 4; ++d8) {
        bf16x8 qv = *(const bf16x8*)(q + d8 * 8);
#pragma unroll
        for (int u = 0; u < 8; ++u) s = fmaf((float)qv[u], ks[d8 * 8 + u], s);
    }
    zb[t] = 1.f / (s + 1e-6f);
}

// ---------------- out[m, h*64+c] = z[m,h] * sum_d q[m,h,d]*kv[h,c,d] --------
__global__ __launch_bounds__(256)
void out_kernel(const __hip_bfloat16* __restrict__ qb,
                const float* __restrict__ kvagg, const float* __restrict__ zb,
                float* __restrict__ out)
{
    __shared__ float lqf[32 * 256];  // 32KB
    __shared__ float lz[32 * 8];
    const int b = blockIdx.y, mt = blockIdx.x;
    const int t = threadIdx.x;
    const long qrow0 = (long)b * Mm + mt * 32;

#pragma unroll
    for (int r = 0; r < 4; ++r) {
        int e = (r * 256 + t) * 8;
        bf16x8 qv = *(const bf16x8*)(qb + qrow0 * 256 + e);
        f32x4 lo = {(float)qv[0], (float)qv[1], (float)qv[2], (float)qv[3]};
        f32x4 hi = {(float)qv[4], (float)qv[5], (float)qv[6], (float)qv[7]};
        *(f32x4*)&lqf[e] = lo;
        *(f32x4*)&lqf[e + 4] = hi;
    }
    lz[t] = zb[qrow0 * 8 + t];

    float kv0[32], kv1[32];
    const float* kvb = kvagg + (long)b * (Hh * 64 * 32);
#pragma unroll
    for (int d4 = 0; d4 < 8; ++d4) {
        *(f32x4*)&kv0[d4 * 4] = *(const f32x4*)&kvb[(long)t * 32 + d4 * 4];
        *(f32x4*)&kv1[d4 * 4] = *(const f32x4*)&kvb[((long)t + 256) * 32 + d4 * 4];
    }
    __syncthreads();

    const int h0 = t >> 6;
    for (int r = 0; r < 32; ++r) {
        float a0 = 0.f, a1 = 0.f;
        const float* q0 = &lqf[r * 256 + h0 * 32];
        const float* q1 = q0 + 128;
#pragma unroll
        for (int d = 0; d < 32; ++d) {
            a0 = fmaf(q0[d], kv0[d], a0);
            a1 = fmaf(q1[d], kv1[d], a1);
        }
        const float z0 = lz[r * 8 + h0];
        const float z1 = lz[r * 8 + h0 + 4];
        const long ob = (qrow0 + r) * 512;
        out[ob + t] = a0 * z0;
        out[ob + t + 256] = a1 * z1;
    }
}

// ---------------- launch ----------------------------------------------------
extern "C" void kernel_launch(void* const* d_in, const int* in_sizes, int n_in,
                              void* d_out, int out_size, void* d_ws, size_t ws_size,
                              hipStream_t stream)
{
    const float* X  = (const float*)d_in[0];
    const float* Qt = (const float*)d_in[1];
    const float* Wq = (const float*)d_in[2];
    const float* bq = (const float*)d_in[3];
    const float* Wk = (const float*)d_in[4];
    const float* bk = (const float*)d_in[5];
    const float* Wv = (const float*)d_in[6];
    const float* bv = (const float*)d_in[7];
    float* out = (float*)d_out;

    // workspace layout (~100 MB)
    __hip_bfloat16* Xb    = (__hip_bfloat16*)d_ws;                 // 32768*512 (33.5MB)
    __hip_bfloat16* Qb    = Xb + (long)NTOK * Cc;                  // 8192*512  (8.4MB)
    __hip_bfloat16* XbT   = Qb + (long)8192 * Cc;                  // 512*32768 (33.5MB)
    __hip_bfloat16* kT    = XbT + (long)Cc * NTOK;                 // 256*32768 (16.8MB)
    __hip_bfloat16* WkT   = kT + (long)Ll * NTOK;                  // 256*512
    __hip_bfloat16* WqT   = WkT + 256 * 512;                       // 256*512
    __hip_bfloat16* qbuf  = WqT + 256 * 512;                       // 8192*256  (4.2MB)
    float* xk    = (float*)(qbuf + (long)8192 * 256);              // 4*512*256 (2.1MB)
    float* kvagg = xk + (long)4 * 512 * 256;                       // 4*8*64*32
    float* ksum  = kvagg + 4 * 8 * 64 * 32;                        // 4*256
    float* zbuf  = ksum + 4 * 256;                                 // 8192*8
    // xkpart aliases Xb (Xb dead after the kT GEMM; stream-serial): 16MB < 33.5MB
    float* xkpart = (float*)d_ws;

    convert_q<<<2048, 256, 0, stream>>>(Qt, Qb);
    transpose_x<<<dim3(512, 8), 256, 0, stream>>>(X, Xb, XbT);
    transpose_w2<<<1024, 256, 0, stream>>>(Wk, Wq, WkT, WqT);
    // kT[d][n] = elu+1(WkT @ Xb^T + bk):  M=256, N=32768, K=512
    gemm_bt<0><<<dim3(2, 256), 256, 0, stream>>>(WkT, 512, Xb, 512, bk, kT, NTOK, 512);
    // qbuf[m][l] = elu+1(Qb @ WqT^T + bq): M=8192, N=256, K=512
    gemm_bt<1><<<dim3(64, 2), 256, 0, stream>>>(Qb, 512, WqT, 512, bq, qbuf, 256, 512);
    ksum_kernel<<<dim3(256, 4), 256, 0, stream>>>(kT, ksum);
    // xkpart[z][c'][d] = XbT @ kT^T over K-chunk: M=512, N=256, z=(b,ks)
    gemm_bt<2><<<dim3(4, 2, 32), 256, 0, stream>>>(XbT, NTOK, kT, NTOK, nullptr, xkpart, 256, 1024);
    reduce_xk<<<2048, 256, 0, stream>>>(xkpart, xk);
    wv_contract<<<dim3(32, 4), 256, 0, stream>>>(xk, Wv, bv, ksum, kvagg);
    z_kernel<<<256, 256, 0, stream>>>(qbuf, ksum, zbuf);
    out_kernel<<<dim3(64, 4), 256, 0, stream>>>(qbuf, kvagg, zbuf, out);
}

// Round 5
// 238.878 us; speedup vs baseline: 1.0099x; 1.0099x over previous
//
#include <hip/hip_runtime.h>
#include <hip/hip_bf16.h>
#include <stdint.h>

typedef __bf16 bf16x8 __attribute__((ext_vector_type(8)));
typedef float f32x4 __attribute__((ext_vector_type(4)));

#define GLD16(gp, lp) __builtin_amdgcn_global_load_lds( \
    (__attribute__((address_space(1))) void*)(gp),      \
    (__attribute__((address_space(3))) void*)(lp), 16, 0, 0)

// Sizes
#define Bb 4
#define Nn 8192
#define Mm 2048
#define Cc 512
#define Ll 256
#define Hh 8
#define NTOK 32768   // Bb*Nn

// ---------------- prep: Q f32->bf16, WkT, WqT -------------------------------
__global__ __launch_bounds__(256) void prep(
    const float* __restrict__ Q, const float* __restrict__ Wk,
    const float* __restrict__ Wq,
    __hip_bfloat16* __restrict__ Qb, __hip_bfloat16* __restrict__ WkT,
    __hip_bfloat16* __restrict__ WqT)
{
    const int bid = blockIdx.x;
    if (bid < 2048) {
        long i = ((long)bid * 256 + threadIdx.x) * 8;   // < 4194304 exact
        float4 a = *(const float4*)(Q + i);
        float4 b = *(const float4*)(Q + i + 4);
        __hip_bfloat16 t8[8] = {
            __float2bfloat16(a.x), __float2bfloat16(a.y),
            __float2bfloat16(a.z), __float2bfloat16(a.w),
            __float2bfloat16(b.x), __float2bfloat16(b.y),
            __float2bfloat16(b.z), __float2bfloat16(b.w)};
        *(uint4*)(Qb + i) = *(const uint4*)t8;
    } else {
        int idx = (bid - 2048) * 256 + threadIdx.x;     // < 262144
        int k = idx & 131071;
        int j = k >> 9, c = k & 511;
        if (idx < 131072) WkT[k] = __float2bfloat16(Wk[c * 256 + j]);
        else              WqT[k] = __float2bfloat16(Wq[c * 256 + j]);
    }
}

// ---------------- transpose_x: X f32 [32768][512] -> Xb [n][c], XbT [c][n] --
// f32 LDS tile [64][65] (2-way max conflicts), vector global stores.
__global__ __launch_bounds__(256) void transpose_x(
    const float* __restrict__ X,
    __hip_bfloat16* __restrict__ Xb, __hip_bfloat16* __restrict__ XbT)
{
    __shared__ float lt[64][65];   // 16.6 KB
    const int tn = blockIdx.x, tc = blockIdx.y;
    const long n0 = (long)tn * 64;
    const int c0 = tc * 64;
    const int t = threadIdx.x;
    const int rl = t >> 4;           // 0..15
    const int c4 = (t & 15) * 4;     // 0..60
#pragma unroll
    for (int u = 0; u < 4; ++u) {
        const int row = rl + u * 16; // 0..63
        f32x4 a = *(const f32x4*)(X + (n0 + row) * Cc + c0 + c4);
        __hip_bfloat16 b4[4] = {
            __float2bfloat16(a.x), __float2bfloat16(a.y),
            __float2bfloat16(a.z), __float2bfloat16(a.w)};
        *(ushort4*)(&Xb[(n0 + row) * Cc + c0 + c4]) = *(const ushort4*)b4;
        lt[c4 + 0][row] = a.x; lt[c4 + 1][row] = a.y;
        lt[c4 + 2][row] = a.z; lt[c4 + 3][row] = a.w;
    }
    __syncthreads();
#pragma unroll
    for (int u = 0; u < 2; ++u) {
        const int v = u * 256 + t;
        const int c = v >> 3;           // 0..63
        const int n8 = (v & 7) * 8;     // 0..56
        __hip_bfloat16 o8[8];
#pragma unroll
        for (int j = 0; j < 8; ++j) o8[j] = __float2bfloat16(lt[c][n8 + j]);
        *(uint4*)(&XbT[(long)(c0 + c) * NTOK + n0 + n8]) = *(const uint4*)o8;
    }
}

// ---------------- gemm_proj: fused kT-GEMM (+ksum atomics) and q-GEMM -------
// blocks [0,512): kT[d][n] = elu1(WkT @ Xb^T + bk), M=256,N=32768,K=512
// blocks [512,640): qbuf[m][l] = elu1(Qb @ WqT^T + bq), M=8192,N=256,K=512
__global__ __launch_bounds__(256)
void gemm_proj(const __hip_bfloat16* __restrict__ WkT,
               const __hip_bfloat16* __restrict__ Xb,
               const __hip_bfloat16* __restrict__ Qb,
               const __hip_bfloat16* __restrict__ WqT,
               const float* __restrict__ bk, const float* __restrict__ bq,
               __hip_bfloat16* __restrict__ kT, __hip_bfloat16* __restrict__ qbuf,
               float* __restrict__ ksum)
{
    __shared__ char lds[2][16384];
    const bool isK = blockIdx.x < 512;
    const __hip_bfloat16 *A, *B;
    long gm0, gn0;
    if (isK) {
        const int bid = blockIdx.x;
        gm0 = (long)(bid & 1) * 128;
        gn0 = (long)(bid >> 1) * 128;
        A = WkT; B = Xb;
    } else {
        const int b2 = blockIdx.x - 512;
        gm0 = (long)(b2 >> 1) * 128;
        gn0 = (long)(b2 & 1) * 128;
        A = Qb; B = WqT;
    }
    const int tid  = threadIdx.x;
    const int lane = tid & 63;
    const int wv   = tid >> 6;
    const int wm   = wv >> 1, wn = wv & 1;

    const int o0 = tid * 16;
    const int row0 = o0 >> 6;
    const int kb0 = o0 & 63;
    const int o1 = o0 + 4096;
    const int row1 = row0 + 64;
    const char* pA0 = (const char*)A + (gm0 + row0) * 1024 + kb0;
    const char* pA1 = (const char*)A + (gm0 + row1) * 1024 + kb0;
    const char* pB0 = (const char*)B + (gn0 + row0) * 1024 + kb0;
    const char* pB1 = (const char*)B + (gn0 + row1) * 1024 + kb0;

    f32x4 acc[4][4];
#pragma unroll
    for (int i = 0; i < 4; i++)
#pragma unroll
        for (int j = 0; j < 4; j++) acc[i][j] = (f32x4){0.f, 0.f, 0.f, 0.f};

    const int l16 = lane & 15, lq = lane >> 4;
    int aoff[4], boff[4];
#pragma unroll
    for (int i = 0; i < 4; i++) {
        aoff[i] = (wm * 64 + i * 16 + l16) * 64 + lq * 16;
        boff[i] = 8192 + (wn * 64 + i * 16 + l16) * 64 + lq * 16;
    }

    {
        char* bf = lds[0];
        GLD16(pA0, bf + o0); GLD16(pA1, bf + o1);
        GLD16(pB0, bf + 8192 + o0); GLD16(pB1, bf + 8192 + o1);
    }
    __syncthreads();
#pragma unroll 1
    for (int kt = 0; kt < 16; ++kt) {
        const int cur = kt & 1;
        if (kt + 1 < 16) {
            char* bf = lds[cur ^ 1];
            const long kb = (long)(kt + 1) * 64;
            GLD16(pA0 + kb, bf + o0); GLD16(pA1 + kb, bf + o1);
            GLD16(pB0 + kb, bf + 8192 + o0); GLD16(pB1 + kb, bf + 8192 + o1);
        }
        const char* lp = lds[cur];
        bf16x8 af[4], bfr[4];
#pragma unroll
        for (int i = 0; i < 4; i++) af[i]  = *(const bf16x8*)(lp + aoff[i]);
#pragma unroll
        for (int j = 0; j < 4; j++) bfr[j] = *(const bf16x8*)(lp + boff[j]);
#pragma unroll
        for (int i = 0; i < 4; i++)
#pragma unroll
            for (int j = 0; j < 4; j++)
                acc[i][j] = __builtin_amdgcn_mfma_f32_16x16x32_bf16(
                    af[i], bfr[j], acc[i][j], 0, 0, 0);
        __syncthreads();
    }

    // epilogue: C/D layout col=lane&15, row=(lane>>4)*4+reg  [m89-verified]
    if (isK) {
        const int batch = (int)(gn0 >> 13);
#pragma unroll
        for (int i = 0; i < 4; i++) {
            const long gmr = gm0 + wm * 64 + i * 16 + lq * 4;
#pragma unroll
            for (int v = 0; v < 4; v++) {
                const float bias = bk[gmr + v];
                float s = 0.f;
#pragma unroll
                for (int j = 0; j < 4; j++) {
                    const int gn = (int)gn0 + wn * 64 + j * 16 + l16;
                    float x = acc[i][j][v] + bias;
                    x = (x > 0.f) ? x + 1.f : __expf(x);
                    kT[gmr * NTOK + (long)v * NTOK + gn] = __float2bfloat16(x);
                    s += x;
                }
                // reduce over the 16-lane col group (masks 1,2,4,8 stay in-group)
                s += __shfl_xor(s, 1); s += __shfl_xor(s, 2);
                s += __shfl_xor(s, 4); s += __shfl_xor(s, 8);
                if (l16 == 0) atomicAdd(&ksum[batch * 256 + gmr + v], s);
            }
        }
    } else {
#pragma unroll
        for (int i = 0; i < 4; i++) {
            const long gmr = gm0 + wm * 64 + i * 16 + lq * 4;
#pragma unroll
            for (int j = 0; j < 4; j++) {
                const int gn = (int)gn0 + wn * 64 + j * 16 + l16;
                const float bias = bq[gn];
#pragma unroll
                for (int v = 0; v < 4; v++) {
                    float x = acc[i][j][v] + bias;
                    x = (x > 0.f) ? x + 1.f : __expf(x);
                    qbuf[(gmr + v) * 256 + gn] = __float2bfloat16(x);
                }
            }
        }
    }
}

// ---------------- gemm_xk: xkpart[z] = XbT @ kT^T over K-slice --------------
// M=512 (c'), N=256 (d), K split 16x512 per batch; z = b*16+ks (64 slices)
__global__ __launch_bounds__(256)
void gemm_xk(const __hip_bfloat16* __restrict__ XbT,
             const __hip_bfloat16* __restrict__ kT,
             float* __restrict__ xkpart)
{
    __shared__ char lds[2][16384];
    const int tid  = threadIdx.x;
    const int lane = tid & 63;
    const int wv   = tid >> 6;
    const int wm   = wv >> 1, wn = wv & 1;
    const long gm0 = (long)blockIdx.x * 128;
    const long gn0 = (long)blockIdx.y * 128;
    const int z = blockIdx.z;
    const long koff = (long)(z >> 4) * Nn + (long)(z & 15) * 512;

    const int o0 = tid * 16;
    const int row0 = o0 >> 6;
    const int kb0 = o0 & 63;
    const int o1 = o0 + 4096;
    const int row1 = row0 + 64;
    const long sR = (long)NTOK * 2;
    const char* pA0 = (const char*)XbT + (gm0 + row0) * sR + koff * 2 + kb0;
    const char* pA1 = (const char*)XbT + (gm0 + row1) * sR + koff * 2 + kb0;
    const char* pB0 = (const char*)kT + (gn0 + row0) * sR + koff * 2 + kb0;
    const char* pB1 = (const char*)kT + (gn0 + row1) * sR + koff * 2 + kb0;

    f32x4 acc[4][4];
#pragma unroll
    for (int i = 0; i < 4; i++)
#pragma unroll
        for (int j = 0; j < 4; j++) acc[i][j] = (f32x4){0.f, 0.f, 0.f, 0.f};

    const int l16 = lane & 15, lq = lane >> 4;
    int aoff[4], boff[4];
#pragma unroll
    for (int i = 0; i < 4; i++) {
        aoff[i] = (wm * 64 + i * 16 + l16) * 64 + lq * 16;
        boff[i] = 8192 + (wn * 64 + i * 16 + l16) * 64 + lq * 16;
    }

    {
        char* bf = lds[0];
        GLD16(pA0, bf + o0); GLD16(pA1, bf + o1);
        GLD16(pB0, bf + 8192 + o0); GLD16(pB1, bf + 8192 + o1);
    }
    __syncthreads();
#pragma unroll 1
    for (int kt = 0; kt < 16; ++kt) {
        const int cur = kt & 1;
        if (kt + 1 < 16) {
            char* bf = lds[cur ^ 1];
            const long kb = (long)(kt + 1) * 64;
            GLD16(pA0 + kb, bf + o0); GLD16(pA1 + kb, bf + o1);
            GLD16(pB0 + kb, bf + 8192 + o0); GLD16(pB1 + kb, bf + 8192 + o1);
        }
        const char* lp = lds[cur];
        bf16x8 af[4], bfr[4];
#pragma unroll
        for (int i = 0; i < 4; i++) af[i]  = *(const bf16x8*)(lp + aoff[i]);
#pragma unroll
        for (int j = 0; j < 4; j++) bfr[j] = *(const bf16x8*)(lp + boff[j]);
#pragma unroll
        for (int i = 0; i < 4; i++)
#pragma unroll
            for (int j = 0; j < 4; j++)
                acc[i][j] = __builtin_amdgcn_mfma_f32_16x16x32_bf16(
                    af[i], bfr[j], acc[i][j], 0, 0, 0);
        __syncthreads();
    }

    float* Cf = xkpart + (long)z * 131072;
#pragma unroll
    for (int i = 0; i < 4; i++) {
        const long gmr = gm0 + wm * 64 + i * 16 + lq * 4;
#pragma unroll
        for (int j = 0; j < 4; j++) {
            const int gn = (int)gn0 + wn * 64 + j * 16 + l16;
#pragma unroll
            for (int v = 0; v < 4; v++)
                Cf[(gmr + v) * 256 + gn] = acc[i][j][v];
        }
    }
}

// ---------------- reduce xkpart (16 K-splits per batch) -> xk ---------------
__global__ __launch_bounds__(256)
void reduce_xk(const float* __restrict__ part, float* __restrict__ xk)
{
    int idx = blockIdx.x * 256 + threadIdx.x;   // < 524288 (=4*512*256)
    int b = idx >> 17, r = idx & 131071;
    const float* p = part + (long)b * 16 * 131072 + r;
    float s = 0.f;
#pragma unroll
    for (int ks = 0; ks < 16; ++ks) s += p[(long)ks * 131072];
    xk[idx] = s;
}

// ---------------- wv_contract: kvagg[b,h,c,d] = Wv^T . xk + bv*ksum ---------
__global__ __launch_bounds__(256)
void wv_contract(const float* __restrict__ xk, const float* __restrict__ Wv,
                 const float* __restrict__ bv, const float* __restrict__ ksum,
                 float* __restrict__ kvagg)
{
    __shared__ float xs[512][32];    // 64KB
    __shared__ float wvs[512][16];   // 32KB
    const int chg = blockIdx.x;      // 0..31 (16 channels each)
    const int b = blockIdx.y;
    const int t = threadIdx.x;
    const int ch0 = chg * 16;
    const int h = ch0 >> 6;
    const float* xb = xk + (long)b * 131072 + h * 32;
#pragma unroll
    for (int u = 0; u < 16; ++u) {
        const int v = u * 256 + t;
        const int row = v >> 3, cq = (v & 7) * 4;
        *(f32x4*)&xs[row][cq] = *(const f32x4*)&xb[(long)row * 256 + cq];
    }
#pragma unroll
    for (int u = 0; u < 8; ++u) {
        const int v = u * 256 + t;
        const int row = v >> 2, q = (v & 3) * 4;
        *(f32x4*)&wvs[row][q] = *(const f32x4*)&Wv[(long)row * 512 + ch0 + q];
    }
    __syncthreads();
    const int ch_l = t >> 4;            // 0..15
    const int d0 = (t & 15) * 2;        // 0,2..30
    const int ch = ch0 + ch_l;
    float a0 = 0.f, a1 = 0.f;
#pragma unroll 8
    for (int c = 0; c < 512; ++c) {
        const float w = wvs[c][ch_l];
        a0 = fmaf(w, xs[c][d0], a0);
        a1 = fmaf(w, xs[c][d0 + 1], a1);
    }
    const float bvv = bv[ch];
    const float* ks = ksum + b * 256 + h * 32;
    a0 += bvv * ks[d0];
    a1 += bvv * ks[d0 + 1];
    float* op = kvagg + (((long)(b * 8 + h) * 64 + (ch & 63)) * 32);
    op[d0] = a0;
    op[d0 + 1] = a1;
}

// ---------------- out_z: z inline + out ------------------------------------
__global__ __launch_bounds__(256)
void out_z(const __hip_bfloat16* __restrict__ qb,
           const float* __restrict__ kvagg, const float* __restrict__ ksum,
           float* __restrict__ out)
{
    __shared__ float lqf[32 * 256];  // 32KB
    __shared__ float lks[256];
    __shared__ float lz[256];
    const int b = blockIdx.y, mt = blockIdx.x;
    const int t = threadIdx.x;
    const long qrow0 = (long)b * Mm + mt * 32;

#pragma unroll
    for (int r = 0; r < 4; ++r) {
        int e = (r * 256 + t) * 8;
        bf16x8 qv = *(const bf16x8*)(qb + qrow0 * 256 + e);
        f32x4 lo = {(float)qv[0], (float)qv[1], (float)qv[2], (float)qv[3]};
        f32x4 hi = {(float)qv[4], (float)qv[5], (float)qv[6], (float)qv[7]};
        *(f32x4*)&lqf[e] = lo;
        *(f32x4*)&lqf[e + 4] = hi;
    }
    lks[t] = ksum[b * 256 + t];

    // kv registers: pair0 = t, pair1 = t+256
    float kv0[32], kv1[32];
    const float* kvb = kvagg + (long)b * (Hh * 64 * 32);
#pragma unroll
    for (int d4 = 0; d4 < 8; ++d4) {
        *(f32x4*)&kv0[d4 * 4] = *(const f32x4*)&kvb[(long)t * 32 + d4 * 4];
        *(f32x4*)&kv1[d4 * 4] = *(const f32x4*)&kvb[((long)t + 256) * 32 + d4 * 4];
    }
    __syncthreads();

    // z: thread t handles (r = t>>3, h = t&7); lz index = r*8+h = t
    {
        const int r = t >> 3, h = t & 7;
        const float* q = &lqf[r * 256 + h * 32];
        const float* ks = &lks[h * 32];
        float s = 0.f;
#pragma unroll
        for (int d = 0; d < 32; ++d) s = fmaf(q[d], ks[d], s);
        lz[t] = 1.f / (s + 1e-6f);
    }
    __syncthreads();

    const int h0 = t >> 6;
    for (int r = 0; r < 32; ++r) {
        float a0 = 0.f, a1 = 0.f;
        const float* q0 = &lqf[r * 256 + h0 * 32];
        const float* q1 = q0 + 128;
#pragma unroll
        for (int d = 0; d < 32; ++d) {
            a0 = fmaf(q0[d], kv0[d], a0);
            a1 = fmaf(q1[d], kv1[d], a1);
        }
        const float z0 = lz[r * 8 + h0];
        const float z1 = lz[r * 8 + h0 + 4];
        const long ob = (qrow0 + r) * 512;
        out[ob + t] = a0 * z0;
        out[ob + t + 256] = a1 * z1;
    }
}

// ---------------- launch ----------------------------------------------------
extern "C" void kernel_launch(void* const* d_in, const int* in_sizes, int n_in,
                              void* d_out, int out_size, void* d_ws, size_t ws_size,
                              hipStream_t stream)
{
    const float* X  = (const float*)d_in[0];
    const float* Qt = (const float*)d_in[1];
    const float* Wq = (const float*)d_in[2];
    const float* bq = (const float*)d_in[3];
    const float* Wk = (const float*)d_in[4];
    const float* bk = (const float*)d_in[5];
    const float* Wv = (const float*)d_in[6];
    const float* bv = (const float*)d_in[7];
    float* out = (float*)d_out;

    // workspace layout (~99 MB of 256 MiB)
    __hip_bfloat16* Xb    = (__hip_bfloat16*)d_ws;                 // 32768*512 (33.55MB)
    __hip_bfloat16* Qb    = Xb + (long)NTOK * Cc;                  // 8192*512
    __hip_bfloat16* XbT   = Qb + (long)8192 * Cc;                  // 512*32768
    __hip_bfloat16* kT    = XbT + (long)Cc * NTOK;                 // 256*32768
    __hip_bfloat16* WkT   = kT + (long)Ll * NTOK;                  // 256*512
    __hip_bfloat16* WqT   = WkT + 256 * 512;                       // 256*512
    __hip_bfloat16* qbuf  = WqT + 256 * 512;                       // 8192*256
    float* xk    = (float*)(qbuf + (long)8192 * 256);              // 4*512*256
    float* kvagg = xk + (long)4 * 512 * 256;                       // 4*8*64*32
    float* ksum  = kvagg + 4 * 8 * 64 * 32;                        // 4*256
    // xkpart aliases Xb (dead after gemm_proj): 64*131072*4B = 33.55MB exact
    float* xkpart = (float*)d_ws;

    hipMemsetAsync(ksum, 0, 4 * 256 * sizeof(float), stream);
    prep<<<3072, 256, 0, stream>>>(Qt, Wk, Wq, Qb, WkT, WqT);
    transpose_x<<<dim3(512, 8), 256, 0, stream>>>(X, Xb, XbT);
    gemm_proj<<<640, 256, 0, stream>>>(WkT, Xb, Qb, WqT, bk, bq, kT, qbuf, ksum);
    gemm_xk<<<dim3(4, 2, 64), 256, 0, stream>>>(XbT, kT, xkpart);
    reduce_xk<<<2048, 256, 0, stream>>>(xkpart, xk);
    wv_contract<<<dim3(32, 4), 256, 0, stream>>>(xk, Wv, bv, ksum, kvagg);
    out_z<<<dim3(64, 4), 256, 0, stream>>>(qbuf, kvagg, ksum, out);
}